// Round 17
// baseline (1013.412 us; speedup 1.0000x reference)
//
#include <hip/hip_runtime.h>
#include <math.h>

#define DIM 512
#define HEADS 16
#define PD 32
#define NSEQ 2048
#define BATCH 4
#define HIDDEN 2048
#define LOG2E 1.44269504088896f

typedef __attribute__((ext_vector_type(8))) __bf16 bf16x8;
typedef __attribute__((ext_vector_type(4))) float f32x4;
typedef __attribute__((ext_vector_type(16))) float f32x16;

__device__ __forceinline__ ushort f2bf(float f) {
    unsigned u = __float_as_uint(f);
    u = (u + 0x7FFFu + ((u >> 16) & 1u)) >> 16;
    return (ushort)u;
}

__device__ __forceinline__ float bf2f(ushort u) {
    return __uint_as_float(((unsigned)u) << 16);
}

__device__ __forceinline__ unsigned cvtpk_bf16(float lo, float hi) {
    unsigned r;
    asm("v_cvt_pk_bf16_f32 %0, %1, %2" : "=v"(r) : "v"(lo), "v"(hi));
    return r;
}

__device__ __forceinline__ float exp2_fast(float x) {
    float r;
    asm("v_exp_f32 %0, %1" : "=v"(r) : "v"(x));
    return r;
}

typedef __attribute__((address_space(1))) const unsigned int g_u32;
typedef __attribute__((address_space(3))) unsigned int l_u32;
__device__ __forceinline__ void gload16(const void* g, void* l) {
    __builtin_amdgcn_global_load_lds((g_u32*)g, (l_u32*)l, 16, 0, 0);
}

__device__ __forceinline__ float gelu_exact(float v) {
    return 0.5f * v * (1.0f + erff(v * 0.70710678118654752f));
}

// 5 weight transposes (W[K][N] fp32 -> Wt[N][K] bf16) + x1/x2 fp32->bf16
// conversion + split-K semaphore zeroing, all in one launch.
__global__ __launch_bounds__(256)
void tr_all_kernel(const float* __restrict__ q_w, const float* __restrict__ kv_w,
                   const float* __restrict__ qkv_w, const float* __restrict__ fc1_w,
                   const float* __restrict__ fc2_w, ushort* __restrict__ wtb,
                   const float* __restrict__ x1, const float* __restrict__ x2,
                   ushort* __restrict__ x1b, ushort* __restrict__ x2b,
                   unsigned* __restrict__ ctr)
{
    const int bid = blockIdx.x;
    if (bid == 7680) {           // zero 2048 semaphores (2 attentions x 1024)
        uint2 z = {0u, 0u};
        *(uint2*)&ctr[threadIdx.x * 8]     = z;
        *(uint2*)&ctr[threadIdx.x * 8 + 2] = z;
        *(uint2*)&ctr[threadIdx.x * 8 + 4] = z;
        *(uint2*)&ctr[threadIdx.x * 8 + 6] = z;
        return;
    }
    if (bid >= 3584) {
        int cb = bid - 3584;
        const float* src = (cb < 2048) ? x1 : x2;
        ushort* dst = (cb < 2048) ? x1b : x2b;
        size_t base = (size_t)(cb & 2047) * 2048 + threadIdx.x * 8;
        float4 f0 = *(const float4*)&src[base];
        float4 f1 = *(const float4*)&src[base + 4];
        union { ushort u[8]; uint4 v; } t;
        t.u[0] = f2bf(f0.x); t.u[1] = f2bf(f0.y); t.u[2] = f2bf(f0.z); t.u[3] = f2bf(f0.w);
        t.u[4] = f2bf(f1.x); t.u[5] = f2bf(f1.y); t.u[6] = f2bf(f1.z); t.u[7] = f2bf(f1.w);
        *(uint4*)&dst[base] = t.v;
        return;
    }
    __shared__ float t[32][33];
    const float* W; ushort* Wt; int K, N, lb;
    if (bid < 256)       { W = q_w;   Wt = wtb;           K = 512;  N = 512;  lb = bid; }
    else if (bid < 768)  { W = kv_w;  Wt = wtb + 262144;  K = 512;  N = 1024; lb = bid - 256; }
    else if (bid < 1536) { W = qkv_w; Wt = wtb + 786432;  K = 512;  N = 1536; lb = bid - 768; }
    else if (bid < 2560) { W = fc1_w; Wt = wtb + 1572864; K = 512;  N = 2048; lb = bid - 1536; }
    else                 { W = fc2_w; Wt = wtb + 2621440; K = 2048; N = 512;  lb = bid - 2560; }
    const int nx = N / 32;
    const int n0 = (lb % nx) * 32, k0 = (lb / nx) * 32;
    const int tid = threadIdx.x;
    const int c = tid & 31, r0 = tid >> 5;
    #pragma unroll
    for (int i = 0; i < 4; ++i) {
        int r = r0 + i * 8;
        t[r][c] = W[(size_t)(k0 + r) * N + n0 + c];
    }
    __syncthreads();
    #pragma unroll
    for (int i = 0; i < 4; ++i) {
        int r = r0 + i * 8;
        Wt[(size_t)(n0 + r) * K + k0 + c] = f2bf(t[c][r]);
    }
}

// bf16 MFMA GEMM, bf16 A, global_load_lds double-buffered 1-barrier pipeline
// (m97 structure). Templated on NT (N-frags per wave): BN = 32*NT.
template<int EPI, int NT>
__global__ __launch_bounds__(256)
void mgemm_bf(const ushort* __restrict__ Ap, const ushort* __restrict__ Bt,
              const float* __restrict__ bias, const float* __restrict__ resp,
              void* __restrict__ Cp, ushort* __restrict__ vtp,
              int M, int K, int Nc, int qcols, int vcol0)
{
    const int BN = 32 * NT;
    __shared__ __align__(16) ushort As[2][128 * 32];
    __shared__ __align__(16) ushort Bs[2][BN * 32];

    const int tid = threadIdx.x;
    const int wid = tid >> 6, ln = tid & 63;
    const int g = ln >> 4, c = ln & 15;
    const int wr = wid >> 1, wc = wid & 1;

    const int nwg = gridDim.x * gridDim.y;
    const int lid = blockIdx.y * gridDim.x + blockIdx.x;
    const int wg  = (lid & 7) * (nwg >> 3) + (lid >> 3);
    const int by = wg / gridDim.x, bx = wg % gridDim.x;
    const int row0 = by * 128, col0 = bx * BN;

    const f32x4 fzero = {0.f, 0.f, 0.f, 0.f};
    f32x4 acc[4][NT];
    #pragma unroll
    for (int i = 0; i < 4; ++i)
        #pragma unroll
        for (int j = 0; j < NT; ++j) acc[i][j] = fzero;

    const ushort* asrc[2];
    const ushort* bsrc[NT / 2];
    #pragma unroll
    for (int i = 0; i < 2; ++i) {
        int p = i * 256 + wid * 64 + ln;
        int row = p >> 2;
        int q4 = (p & 3) ^ ((row >> 1) & 3);
        asrc[i] = Ap + (size_t)(row0 + row) * K + q4 * 8;
    }
    #pragma unroll
    for (int i = 0; i < NT / 2; ++i) {
        int p = i * 256 + wid * 64 + ln;
        int row = p >> 2;
        int q4 = (p & 3) ^ ((row >> 1) & 3);
        bsrc[i] = Bt + (size_t)(col0 + row) * K + q4 * 8;
    }

    auto gstage = [&](int bi, int kk) {
        #pragma unroll
        for (int i = 0; i < 2; ++i)
            gload16(asrc[i] + kk, &As[bi][(i * 256 + wid * 64) * 8]);
        #pragma unroll
        for (int i = 0; i < NT / 2; ++i)
            gload16(bsrc[i] + kk, &Bs[bi][(i * 256 + wid * 64) * 8]);
    };

    const int ps = (c >> 1) & 3;
    const int nk = K / 32;

    gstage(0, 0);

    for (int ks = 0; ks < nk; ++ks) {
        __syncthreads();
        if (ks + 1 < nk) gstage((ks + 1) & 1, (ks + 1) * 32);
        const ushort* Ab = As[ks & 1];
        const ushort* Bb = Bs[ks & 1];

        bf16x8 a[4], b[NT];
        #pragma unroll
        for (int mt = 0; mt < 4; ++mt)
            a[mt] = *(const bf16x8*)&Ab[(wr * 64 + mt * 16 + c) * 32 + ((g ^ ps) * 8)];
        #pragma unroll
        for (int nt = 0; nt < NT; ++nt)
            b[nt] = *(const bf16x8*)&Bb[(wc * (16 * NT) + nt * 16 + c) * 32 + ((g ^ ps) * 8)];

        #pragma unroll
        for (int mt = 0; mt < 4; ++mt)
            #pragma unroll
            for (int nt = 0; nt < NT; ++nt)
                acc[mt][nt] = __builtin_amdgcn_mfma_f32_16x16x32_bf16(a[mt], b[nt], acc[mt][nt], 0, 0, 0);
    }

    // ---- epilogue ----
    float bs[NT];
    #pragma unroll
    for (int nt = 0; nt < NT; ++nt) bs[nt] = bias[col0 + wc * (16 * NT) + nt * 16 + c];

    #pragma unroll
    for (int mt = 0; mt < 4; ++mt) {
        const int rb = row0 + wr * 64 + mt * 16 + g * 4;
        #pragma unroll
        for (int nt = 0; nt < NT; ++nt) {
            const int col = col0 + wc * (16 * NT) + nt * 16 + c;
            if (EPI == 3 && col >= vcol0) {
                int cc = col - vcol0;
                int hh = cc >> 5, pd = cc & 31;
                int bq = rb >> 11, ntok = rb & 2047;
                union { ushort u[4]; uint2 v; } pk;
                #pragma unroll
                for (int reg = 0; reg < 4; ++reg)
                    pk.u[reg] = f2bf(acc[mt][nt][reg] + bs[nt]);
                *(uint2*)&vtp[((size_t)(bq * 16 + hh) * 32 + pd) * 2048 + ntok] = pk.v;
            } else {
                #pragma unroll
                for (int reg = 0; reg < 4; ++reg) {
                    int r = rb + reg;
                    float v = acc[mt][nt][reg] + bs[nt];
                    if (EPI == 1) {
                        ((ushort*)Cp)[(size_t)r * Nc + col] = f2bf(gelu_exact(v));
                    } else if (EPI == 2) {
                        ((float*)Cp)[(size_t)r * Nc + col] = v + resp[(size_t)r * Nc + col];
                    } else {
                        float v2 = (col < qcols) ? v * LOG2E : v;
                        ((ushort*)Cp)[(size_t)r * Nc + col] = f2bf(v2);
                    }
                }
            }
        }
    }
}

// MFMA flash attention, KV-split x2 with LAST-FINISHER MERGE (split-K
// semaphore, no spin): both half-blocks of a (bh,qt) pair write bf16
// partials + l, threadfence, atomicAdd; the second finisher reads BOTH
// partials (symmetric => deterministic) and runs the fused res+LN epilogue.
// XCD swizzle keeps both halves on one XCD => partial reads are L2-hot.
// Flag broadcast reuses dead Klds (no extra LDS; 5 blocks/CU preserved).
__global__ __launch_bounds__(256)
void attn_part_kernel(const ushort* __restrict__ qb_, int qstride, int qoff,
                      const ushort* __restrict__ kb_, int kstride, int koff,
                      const ushort* __restrict__ vtg,
                      ushort* __restrict__ opart, float* __restrict__ lpart,
                      unsigned* __restrict__ ctr,
                      const float* res, const float* __restrict__ gptr,
                      const float* __restrict__ bptr,
                      float* nf32, ushort* __restrict__ nb16)
{
    __shared__ __align__(16) ushort Klds[2][128 * 32];
    __shared__ __align__(16) ushort Vtlds[2][32 * 128];

    const int tid = threadIdx.x;
    const int w   = tid >> 6;
    const int ln  = tid & 63;
    const int c32 = ln & 31;
    const int hi  = ln >> 5;

    const int bid = blockIdx.x;
    const int half = bid >> 10;
    const int sb = bid & 1023;
    const int xcd = sb & 7, jj = sb >> 3;
    const int bh = xcd + 8 * (jj >> 4);
    const int qt = jj & 15;
    const int b = bh >> 4, h = bh & 15;
    const size_t rowbase = (size_t)b * NSEQ;
    const int qt0 = qt * 128 + w * 32;
    const int n = qt0 + c32;
    const int t0base = half * (NSEQ / 2);

    ushort* oph = opart + (size_t)half * 8192 * 512;
    float*  lph = lpart + (size_t)half * 64 * 2048;

    bf16x8 qfrag[2];
    #pragma unroll
    for (int ph = 0; ph < 2; ++ph)
        qfrag[ph] = *(const bf16x8*)(qb_ + (rowbase + n) * qstride + qoff
                                     + h * PD + ph * 16 + hi * 8);

    const ushort* ks[2];
    const ushort* vs[2];
    int kd[2], vd[2];
    #pragma unroll
    for (int i = 0; i < 2; ++i) {
        int ch = 2 * w + i;
        int kvc = ch * 16 + (ln >> 2);
        int q4  = (ln & 3) ^ ((kvc >> 1) & 3);
        ks[i] = kb_ + (rowbase + t0base + kvc) * kstride + koff + h * PD + q4 * 8;
        kd[i] = ch * 512;
        int pdc = ch * 4 + (ln >> 4);
        int kv0 = ((ln & 15) ^ (pdc & 15)) * 8;
        vs[i] = vtg + ((size_t)bh * PD + pdc) * 2048 + t0base + kv0;
        vd[i] = ch * 512;
    }

#define STAGE(bi, trow)                                              \
    {                                                                \
        gload16(ks[0] + (size_t)(trow) * kstride, &Klds[bi][kd[0]]); \
        gload16(ks[1] + (size_t)(trow) * kstride, &Klds[bi][kd[1]]); \
        gload16(vs[0] + (trow), &Vtlds[bi][vd[0]]);                  \
        gload16(vs[1] + (trow), &Vtlds[bi][vd[1]]);                  \
    }

    f32x16 oacc, zero16;
    #pragma unroll
    for (int i = 0; i < 16; ++i) { oacc[i] = 0.f; zero16[i] = 0.f; }
    float l = 0.f;

    STAGE(0, 0);

    for (int t = 0; t < NSEQ / 256; ++t) {
        __syncthreads();
        if (t < NSEQ / 256 - 1) STAGE((t + 1) & 1, (t + 1) * 128);
        const ushort* Kb = Klds[t & 1];
        const ushort* Vb = Vtlds[t & 1];

        #pragma unroll
        for (int hh = 0; hh < 2; ++hh) {
            bf16x8 kf[2][2];
            #pragma unroll
            for (int kt = 0; kt < 2; ++kt)
                #pragma unroll
                for (int ph = 0; ph < 2; ++ph) {
                    int slot = (2 * ph + hi) ^ ((c32 >> 1) & 3);
                    kf[kt][ph] = *(const bf16x8*)&Kb[(hh * 64 + kt * 32 + c32) * 32 + slot * 8];
                }
            bf16x8 vf[4];
            #pragma unroll
            for (int j = 0; j < 4; ++j) {
                int slot = (hh * 8 + 2 * j + hi) ^ (c32 & 15);
                vf[j] = *(const bf16x8*)&Vb[c32 * 128 + slot * 8];
            }

            f32x16 st[2];
            __builtin_amdgcn_s_setprio(1);
            #pragma unroll
            for (int kt = 0; kt < 2; ++kt) {
                st[kt] = __builtin_amdgcn_mfma_f32_32x32x16_bf16(kf[kt][0], qfrag[0], zero16, 0, 0, 0);
                st[kt] = __builtin_amdgcn_mfma_f32_32x32x16_bf16(kf[kt][1], qfrag[1], st[kt], 0, 0, 0);
            }
            __builtin_amdgcn_s_setprio(0);

            float r0 = 0.f, r1 = 0.f, r2 = 0.f, r3 = 0.f;
            #pragma unroll
            for (int kt = 0; kt < 2; ++kt) {
                #pragma unroll
                for (int i = 0; i < 4; ++i) {
                    float p0 = exp2_fast(st[kt][i * 4 + 0]);
                    float p1 = exp2_fast(st[kt][i * 4 + 1]);
                    float p2 = exp2_fast(st[kt][i * 4 + 2]);
                    float p3 = exp2_fast(st[kt][i * 4 + 3]);
                    st[kt][i * 4 + 0] = p0; r0 += p0;
                    st[kt][i * 4 + 1] = p1; r1 += p1;
                    st[kt][i * 4 + 2] = p2; r2 += p2;
                    st[kt][i * 4 + 3] = p3; r3 += p3;
                }
            }
            float rsum = (r0 + r1) + (r2 + r3);
            rsum += __shfl_xor(rsum, 32);
            l += rsum;

            unsigned wpk[2][4][2];
            #pragma unroll
            for (int kt = 0; kt < 2; ++kt)
                #pragma unroll
                for (int rg = 0; rg < 4; ++rg) {
                    wpk[kt][rg][0] = cvtpk_bf16(st[kt][rg * 4 + 0], st[kt][rg * 4 + 1]);
                    wpk[kt][rg][1] = cvtpk_bf16(st[kt][rg * 4 + 2], st[kt][rg * 4 + 3]);
                }

            __builtin_amdgcn_s_setprio(1);
            #pragma unroll
            for (int j = 0; j < 4; ++j) {
                int kt = j >> 1, rg0 = 2 * (j & 1);
                unsigned x0 = wpk[kt][rg0][0], y0 = wpk[kt][rg0 + 1][0];
                unsigned x1 = wpk[kt][rg0][1], y1 = wpk[kt][rg0 + 1][1];
                asm("v_permlane32_swap_b32 %0, %1" : "+v"(x0), "+v"(y0));
                asm("v_permlane32_swap_b32 %0, %1" : "+v"(x1), "+v"(y1));
                union { unsigned u[4]; bf16x8 v; } pf;
                pf.u[0] = x0; pf.u[1] = x1; pf.u[2] = y0; pf.u[3] = y1;
                oacc = __builtin_amdgcn_mfma_f32_32x32x16_bf16(vf[j], pf.v, oacc, 0, 0, 0);
            }
            __builtin_amdgcn_s_setprio(0);
        }
    }
#undef STAGE

    // ---- write own partial (bf16, heads-merge permuted) + l ----
    const int row2 = h * 128 + (n >> 4);
    const int colb = (n & 15) * PD;
    const size_t rowoff = (rowbase + row2) * DIM;
    #pragma unroll
    for (int ch = 0; ch < 4; ++ch) {
        const int off = colb + ch * 8 + hi * 4;
        uint2 pk = {cvtpk_bf16(oacc[ch * 4 + 0], oacc[ch * 4 + 1]),
                    cvtpk_bf16(oacc[ch * 4 + 2], oacc[ch * 4 + 3])};
        *(uint2*)&oph[rowoff + off] = pk;
    }
    if (hi == 0) lph[(size_t)bh * 2048 + n] = l;

    // ---- split-K semaphore: second finisher merges ----
    __threadfence();
    __syncthreads();                       // Klds dead; all writes issued+fenced
    int* flag = (int*)&Klds[0][0];
    if (tid == 0) flag[0] = (int)atomicAdd(&ctr[sb], 1u);
    __syncthreads();
    if (flag[0] != 1) return;              // first finisher exits
    __threadfence();                       // acquire: other half's writes visible

    // ---- merge (symmetric: read BOTH partials) + residual + LayerNorm ----
    const float linv = 1.0f / (lpart[(size_t)bh * 2048 + n]
                               + lpart[(size_t)64 * 2048 + (size_t)bh * 2048 + n]);
    float xv[16];
    float s = 0.f, ss = 0.f;
    #pragma unroll
    for (int ch = 0; ch < 4; ++ch) {
        const int off = colb + ch * 8 + hi * 4;
        uint2 a = *(const uint2*)&opart[rowoff + off];
        uint2 b2 = *(const uint2*)&opart[(size_t)8192 * 512 + rowoff + off];
        float4 r4 = *(const float4*)&res[rowoff + off];
        float e0 = bf2f((ushort)(a.x & 0xFFFF)) + bf2f((ushort)(b2.x & 0xFFFF));
        float e1 = bf2f((ushort)(a.x >> 16))    + bf2f((ushort)(b2.x >> 16));
        float e2 = bf2f((ushort)(a.y & 0xFFFF)) + bf2f((ushort)(b2.y & 0xFFFF));
        float e3 = bf2f((ushort)(a.y >> 16))    + bf2f((ushort)(b2.y >> 16));
        float x0 = r4.x + e0 * linv;
        float x1 = r4.y + e1 * linv;
        float x2v = r4.z + e2 * linv;
        float x3 = r4.w + e3 * linv;
        xv[ch * 4 + 0] = x0; xv[ch * 4 + 1] = x1;
        xv[ch * 4 + 2] = x2v; xv[ch * 4 + 3] = x3;
        s += (x0 + x1) + (x2v + x3);
        ss += (x0 * x0 + x1 * x1) + (x2v * x2v + x3 * x3);
    }
    s += __shfl_xor(s, 1);  ss += __shfl_xor(ss, 1);
    s += __shfl_xor(s, 2);  ss += __shfl_xor(ss, 2);
    s += __shfl_xor(s, 4);  ss += __shfl_xor(ss, 4);
    s += __shfl_xor(s, 8);  ss += __shfl_xor(ss, 8);
    s += __shfl_xor(s, 32); ss += __shfl_xor(ss, 32);
    float mu = s * (1.0f / DIM);
    float var = ss * (1.0f / DIM) - mu * mu;
    float rr = rsqrtf(var + 1e-5f);

    #pragma unroll
    for (int ch = 0; ch < 4; ++ch) {
        const int off = colb + ch * 8 + hi * 4;
        float4 g4 = *(const float4*)&gptr[off];
        float4 b4 = *(const float4*)&bptr[off];
        float y0 = (xv[ch * 4 + 0] - mu) * rr * g4.x + b4.x;
        float y1 = (xv[ch * 4 + 1] - mu) * rr * g4.y + b4.y;
        float y2 = (xv[ch * 4 + 2] - mu) * rr * g4.z + b4.z;
        float y3 = (xv[ch * 4 + 3] - mu) * rr * g4.w + b4.w;
        float4 yv = {y0, y1, y2, y3};
        *(float4*)&nf32[rowoff + off] = yv;
        uint2 pk = {cvtpk_bf16(y0, y1), cvtpk_bf16(y2, y3)};
        *(uint2*)&nb16[rowoff + off] = pk;
    }
}

extern "C" void kernel_launch(void* const* d_in, const int* in_sizes, int n_in,
                              void* d_out, int out_size, void* d_ws, size_t ws_size,
                              hipStream_t stream)
{
    const float* x1     = (const float*)d_in[0];
    const float* x2     = (const float*)d_in[1];
    const float* qkv_w  = (const float*)d_in[2];
    const float* qkv_b  = (const float*)d_in[3];
    const float* q_w    = (const float*)d_in[4];
    const float* q_b    = (const float*)d_in[5];
    const float* kv_w   = (const float*)d_in[6];
    const float* kv_b   = (const float*)d_in[7];
    const float* norm_g = (const float*)d_in[8];
    const float* norm_b = (const float*)d_in[9];
    const float* fc1_w  = (const float*)d_in[10];
    const float* fc1_b  = (const float*)d_in[11];
    const float* fc2_w  = (const float*)d_in[12];
    const float* fc2_b  = (const float*)d_in[13];
    float* out = (float*)d_out;
    float* ws  = (float*)d_ws;

    const int M = BATCH * NSEQ;  // 8192
    const int BIG = 1 << 30;

    // ws layout (float offsets), 100 MB total, all regions disjoint:
    // [0,2M) weights | [2M,10M) proj_u | [10.5M,12.5M) VtG
    // [12.5M,12.75M) lpart | [12.75M,+2048 ints) ctr | [13M,17M) n1f32
    // [17M,19M) n1b16 (alias x1b) | [19M,21M) n2b16 (alias x2b)
    // [21M,25M) opart (2 halves x 8192x512 bf16)
    ushort* wtb    = (ushort*)ws;
    ushort* q_wt   = wtb;
    ushort* kv_wt  = wtb + 262144;
    ushort* qkv_wt = wtb + 786432;
    ushort* fc1_wt = wtb + 1572864;
    ushort* fc2_wt = wtb + 2621440;
    ushort* proj_u = (ushort*)(ws + (size_t)2 * 1024 * 1024);
    ushort* kvb16  = proj_u;                            // 8192x1024
    ushort* qb16   = proj_u + (size_t)8192 * 1024;      // 8192x512
    ushort* qkvb16 = proj_u;                            // 8192x1536
    ushort* hbuf   = proj_u;                            // 8192x2048
    ushort* VtG    = (ushort*)(ws + (size_t)21 * 512 * 1024);   // 10.5M floats
    float*  lpart  = ws + (size_t)25 * 512 * 1024;              // 12.5M floats
    unsigned* ctr  = (unsigned*)(ws + (size_t)51 * 256 * 1024); // 12.75M floats
    float*  n1f32  = ws + (size_t)13 * 1024 * 1024;
    ushort* n1b16  = (ushort*)(ws + (size_t)17 * 1024 * 1024);
    ushort* n2b16  = (ushort*)(ws + (size_t)19 * 1024 * 1024);
    ushort* opart  = (ushort*)(ws + (size_t)21 * 1024 * 1024);
    ushort* x1b    = n1b16;   // alias, temporally disjoint
    ushort* x2b    = n2b16;   // alias, temporally disjoint

    dim3 blk(256);

    tr_all_kernel<<<dim3(7681), blk, 0, stream>>>(
        q_w, kv_w, qkv_w, fc1_w, fc2_w, wtb, x1, x2, x1b, x2b, ctr);

    // ---- cross attention ----
    mgemm_bf<3, 4><<<dim3(1024 / 128, M / 128), blk, 0, stream>>>(
        x1b, kv_wt, kv_b, nullptr, kvb16, VtG, M, DIM, 1024, 0, 512);
    mgemm_bf<3, 2><<<dim3(512 / 64, M / 128), blk, 0, stream>>>(
        x2b, q_wt, q_b, nullptr, qb16, nullptr, M, DIM, 512, 512, BIG);
    attn_part_kernel<<<dim3(2048), blk, 0, stream>>>(
        qb16, 512, 0, kvb16, 1024, 0, VtG, opart, lpart, ctr,
        x2, norm_g, norm_b, n1f32, n1b16);

    // ---- self attention ----
    mgemm_bf<3, 4><<<dim3(1536 / 128, M / 128), blk, 0, stream>>>(
        n1b16, qkv_wt, qkv_b, nullptr, qkvb16, VtG, M, DIM, 1536, 512, 1024);
    attn_part_kernel<<<dim3(2048), blk, 0, stream>>>(
        qkvb16, 1536, 0, qkvb16, 1536, 512, VtG, opart, lpart, ctr + 1024,
        n1f32, norm_g, norm_b, n1f32, n2b16);

    // ---- MLP ----
    mgemm_bf<1, 4><<<dim3(HIDDEN / 128, M / 128), blk, 0, stream>>>(
        n2b16, fc1_wt, fc1_b, nullptr, hbuf, nullptr, M, DIM, HIDDEN, 0, BIG);
    mgemm_bf<2, 2><<<dim3(512 / 64, M / 128), blk, 0, stream>>>(
        hbuf, fc2_wt, fc2_b, n1f32, out, nullptr, M, HIDDEN, DIM, 0, BIG);
}

// Round 18
// 274.044 us; speedup vs baseline: 3.6980x; 3.6980x over previous
//
#include <hip/hip_runtime.h>
#include <math.h>

#define DIM 512
#define HEADS 16
#define PD 32
#define NSEQ 2048
#define BATCH 4
#define HIDDEN 2048
#define LOG2E 1.44269504088896f

typedef __attribute__((ext_vector_type(8))) __bf16 bf16x8;
typedef __attribute__((ext_vector_type(4))) float f32x4;
typedef __attribute__((ext_vector_type(16))) float f32x16;

__device__ __forceinline__ ushort f2bf(float f) {
    unsigned u = __float_as_uint(f);
    u = (u + 0x7FFFu + ((u >> 16) & 1u)) >> 16;
    return (ushort)u;
}

__device__ __forceinline__ unsigned cvtpk_bf16(float lo, float hi) {
    unsigned r;
    asm("v_cvt_pk_bf16_f32 %0, %1, %2" : "=v"(r) : "v"(lo), "v"(hi));
    return r;
}

__device__ __forceinline__ float exp2_fast(float x) {
    float r;
    asm("v_exp_f32 %0, %1" : "=v"(r) : "v"(x));
    return r;
}

typedef __attribute__((address_space(1))) const unsigned int g_u32;
typedef __attribute__((address_space(3))) unsigned int l_u32;
__device__ __forceinline__ void gload16(const void* g, void* l) {
    __builtin_amdgcn_global_load_lds((g_u32*)g, (l_u32*)l, 16, 0, 0);
}

__device__ __forceinline__ float gelu_exact(float v) {
    return 0.5f * v * (1.0f + erff(v * 0.70710678118654752f));
}

// 5 weight transposes (W[K][N] fp32 -> Wt[N][K] bf16) + x1/x2 fp32->bf16
// conversion, all in one launch.
__global__ __launch_bounds__(256)
void tr_all_kernel(const float* __restrict__ q_w, const float* __restrict__ kv_w,
                   const float* __restrict__ qkv_w, const float* __restrict__ fc1_w,
                   const float* __restrict__ fc2_w, ushort* __restrict__ wtb,
                   const float* __restrict__ x1, const float* __restrict__ x2,
                   ushort* __restrict__ x1b, ushort* __restrict__ x2b)
{
    const int bid = blockIdx.x;
    if (bid >= 3584) {
        int cb = bid - 3584;
        const float* src = (cb < 2048) ? x1 : x2;
        ushort* dst = (cb < 2048) ? x1b : x2b;
        size_t base = (size_t)(cb & 2047) * 2048 + threadIdx.x * 8;
        float4 f0 = *(const float4*)&src[base];
        float4 f1 = *(const float4*)&src[base + 4];
        union { ushort u[8]; uint4 v; } t;
        t.u[0] = f2bf(f0.x); t.u[1] = f2bf(f0.y); t.u[2] = f2bf(f0.z); t.u[3] = f2bf(f0.w);
        t.u[4] = f2bf(f1.x); t.u[5] = f2bf(f1.y); t.u[6] = f2bf(f1.z); t.u[7] = f2bf(f1.w);
        *(uint4*)&dst[base] = t.v;
        return;
    }
    __shared__ float t[32][33];
    const float* W; ushort* Wt; int K, N, lb;
    if (bid < 256)       { W = q_w;   Wt = wtb;           K = 512;  N = 512;  lb = bid; }
    else if (bid < 768)  { W = kv_w;  Wt = wtb + 262144;  K = 512;  N = 1024; lb = bid - 256; }
    else if (bid < 1536) { W = qkv_w; Wt = wtb + 786432;  K = 512;  N = 1536; lb = bid - 768; }
    else if (bid < 2560) { W = fc1_w; Wt = wtb + 1572864; K = 512;  N = 2048; lb = bid - 1536; }
    else                 { W = fc2_w; Wt = wtb + 2621440; K = 2048; N = 512;  lb = bid - 2560; }
    const int nx = N / 32;
    const int n0 = (lb % nx) * 32, k0 = (lb / nx) * 32;
    const int tid = threadIdx.x;
    const int c = tid & 31, r0 = tid >> 5;
    #pragma unroll
    for (int i = 0; i < 4; ++i) {
        int r = r0 + i * 8;
        t[r][c] = W[(size_t)(k0 + r) * N + n0 + c];
    }
    __syncthreads();
    #pragma unroll
    for (int i = 0; i < 4; ++i) {
        int r = r0 + i * 8;
        Wt[(size_t)(n0 + r) * K + k0 + c] = f2bf(t[c][r]);
    }
}

// bf16 MFMA GEMM, bf16 A, global_load_lds double-buffered 1-barrier pipeline
// (m97 structure). Templated on NT (N-frags per wave): BN = 32*NT.
// NT=4 -> 128x128 tile; NT=2 -> 128x64 tile (2x grid for the N=512 GEMMs,
// fixes the 1-block/CU latency exposure; NT=2 on kv/qkv measured neutral
// and reverted — round-15).
template<int EPI, int NT>
__global__ __launch_bounds__(256)
void mgemm_bf(const ushort* __restrict__ Ap, const ushort* __restrict__ Bt,
              const float* __restrict__ bias, const float* __restrict__ resp,
              void* __restrict__ Cp, ushort* __restrict__ vtp,
              int M, int K, int Nc, int qcols, int vcol0)
{
    const int BN = 32 * NT;
    __shared__ __align__(16) ushort As[2][128 * 32];
    __shared__ __align__(16) ushort Bs[2][BN * 32];

    const int tid = threadIdx.x;
    const int wid = tid >> 6, ln = tid & 63;
    const int g = ln >> 4, c = ln & 15;
    const int wr = wid >> 1, wc = wid & 1;

    const int nwg = gridDim.x * gridDim.y;
    const int lid = blockIdx.y * gridDim.x + blockIdx.x;
    const int wg  = (lid & 7) * (nwg >> 3) + (lid >> 3);
    const int by = wg / gridDim.x, bx = wg % gridDim.x;
    const int row0 = by * 128, col0 = bx * BN;

    const f32x4 fzero = {0.f, 0.f, 0.f, 0.f};
    f32x4 acc[4][NT];
    #pragma unroll
    for (int i = 0; i < 4; ++i)
        #pragma unroll
        for (int j = 0; j < NT; ++j) acc[i][j] = fzero;

    const ushort* asrc[2];
    const ushort* bsrc[NT / 2];
    #pragma unroll
    for (int i = 0; i < 2; ++i) {
        int p = i * 256 + wid * 64 + ln;
        int row = p >> 2;
        int q4 = (p & 3) ^ ((row >> 1) & 3);
        asrc[i] = Ap + (size_t)(row0 + row) * K + q4 * 8;
    }
    #pragma unroll
    for (int i = 0; i < NT / 2; ++i) {
        int p = i * 256 + wid * 64 + ln;
        int row = p >> 2;
        int q4 = (p & 3) ^ ((row >> 1) & 3);
        bsrc[i] = Bt + (size_t)(col0 + row) * K + q4 * 8;
    }

    auto gstage = [&](int bi, int kk) {
        #pragma unroll
        for (int i = 0; i < 2; ++i)
            gload16(asrc[i] + kk, &As[bi][(i * 256 + wid * 64) * 8]);
        #pragma unroll
        for (int i = 0; i < NT / 2; ++i)
            gload16(bsrc[i] + kk, &Bs[bi][(i * 256 + wid * 64) * 8]);
    };

    const int ps = (c >> 1) & 3;
    const int nk = K / 32;

    gstage(0, 0);

    for (int ks = 0; ks < nk; ++ks) {
        __syncthreads();
        if (ks + 1 < nk) gstage((ks + 1) & 1, (ks + 1) * 32);
        const ushort* Ab = As[ks & 1];
        const ushort* Bb = Bs[ks & 1];

        bf16x8 a[4], b[NT];
        #pragma unroll
        for (int mt = 0; mt < 4; ++mt)
            a[mt] = *(const bf16x8*)&Ab[(wr * 64 + mt * 16 + c) * 32 + ((g ^ ps) * 8)];
        #pragma unroll
        for (int nt = 0; nt < NT; ++nt)
            b[nt] = *(const bf16x8*)&Bb[(wc * (16 * NT) + nt * 16 + c) * 32 + ((g ^ ps) * 8)];

        #pragma unroll
        for (int mt = 0; mt < 4; ++mt)
            #pragma unroll
            for (int nt = 0; nt < NT; ++nt)
                acc[mt][nt] = __builtin_amdgcn_mfma_f32_16x16x32_bf16(a[mt], b[nt], acc[mt][nt], 0, 0, 0);
    }

    // ---- epilogue ----
    float bs[NT];
    #pragma unroll
    for (int nt = 0; nt < NT; ++nt) bs[nt] = bias[col0 + wc * (16 * NT) + nt * 16 + c];

    #pragma unroll
    for (int mt = 0; mt < 4; ++mt) {
        const int rb = row0 + wr * 64 + mt * 16 + g * 4;
        #pragma unroll
        for (int nt = 0; nt < NT; ++nt) {
            const int col = col0 + wc * (16 * NT) + nt * 16 + c;
            if (EPI == 3 && col >= vcol0) {
                int cc = col - vcol0;
                int hh = cc >> 5, pd = cc & 31;
                int bq = rb >> 11, ntok = rb & 2047;
                union { ushort u[4]; uint2 v; } pk;
                #pragma unroll
                for (int reg = 0; reg < 4; ++reg)
                    pk.u[reg] = f2bf(acc[mt][nt][reg] + bs[nt]);
                *(uint2*)&vtp[((size_t)(bq * 16 + hh) * 32 + pd) * 2048 + ntok] = pk.v;
            } else {
                #pragma unroll
                for (int reg = 0; reg < 4; ++reg) {
                    int r = rb + reg;
                    float v = acc[mt][nt][reg] + bs[nt];
                    if (EPI == 1) {
                        ((ushort*)Cp)[(size_t)r * Nc + col] = f2bf(gelu_exact(v));
                    } else if (EPI == 2) {
                        ((float*)Cp)[(size_t)r * Nc + col] = v + resp[(size_t)r * Nc + col];
                    } else {
                        float v2 = (col < qcols) ? v * LOG2E : v;
                        ((ushort*)Cp)[(size_t)r * Nc + col] = f2bf(v2);
                    }
                }
            }
        }
    }
}

// MFMA flash attention + fused residual + LayerNorm epilogue — exact
// round-13/14 kernel (single oacc, 84 VGPR, 24% occupancy, verified fastest).
__global__ __launch_bounds__(256)
void attn_mfma_kernel(const ushort* __restrict__ qb_, int qstride, int qoff,
                      const ushort* __restrict__ kb_, int kstride, int koff,
                      const ushort* __restrict__ vtg,
                      const float* res, const float* __restrict__ gptr,
                      const float* __restrict__ bptr,
                      float* nf32, ushort* __restrict__ nb16)
{
    __shared__ __align__(16) ushort Klds[2][128 * 32];
    __shared__ __align__(16) ushort Vtlds[2][32 * 128];

    const int tid = threadIdx.x;
    const int w   = tid >> 6;
    const int ln  = tid & 63;
    const int c32 = ln & 31;
    const int hi  = ln >> 5;

    const int bid = blockIdx.x;
    const int xcd = bid & 7, jj = bid >> 3;
    const int bh = xcd + 8 * (jj >> 4);
    const int qt = jj & 15;
    const int b = bh >> 4, h = bh & 15;
    const size_t rowbase = (size_t)b * NSEQ;
    const int qt0 = qt * 128 + w * 32;
    const int n = qt0 + c32;

    bf16x8 qfrag[2];
    #pragma unroll
    for (int ph = 0; ph < 2; ++ph)
        qfrag[ph] = *(const bf16x8*)(qb_ + (rowbase + n) * qstride + qoff
                                     + h * PD + ph * 16 + hi * 8);

    const ushort* ks[2];
    const ushort* vs[2];
    int kd[2], vd[2];
    #pragma unroll
    for (int i = 0; i < 2; ++i) {
        int ch = 2 * w + i;
        int kvc = ch * 16 + (ln >> 2);
        int q4  = (ln & 3) ^ ((kvc >> 1) & 3);
        ks[i] = kb_ + (rowbase + kvc) * kstride + koff + h * PD + q4 * 8;
        kd[i] = ch * 512;
        int pdc = ch * 4 + (ln >> 4);
        int kv0 = ((ln & 15) ^ (pdc & 15)) * 8;
        vs[i] = vtg + ((size_t)bh * PD + pdc) * 2048 + kv0;
        vd[i] = ch * 512;
    }

#define STAGE(bi, trow)                                              \
    {                                                                \
        gload16(ks[0] + (size_t)(trow) * kstride, &Klds[bi][kd[0]]); \
        gload16(ks[1] + (size_t)(trow) * kstride, &Klds[bi][kd[1]]); \
        gload16(vs[0] + (trow), &Vtlds[bi][vd[0]]);                  \
        gload16(vs[1] + (trow), &Vtlds[bi][vd[1]]);                  \
    }

    f32x16 oacc, zero16;
    #pragma unroll
    for (int i = 0; i < 16; ++i) { oacc[i] = 0.f; zero16[i] = 0.f; }
    float l = 0.f;

    STAGE(0, 0);

    for (int t = 0; t < NSEQ / 128; ++t) {
        __syncthreads();
        if (t < NSEQ / 128 - 1) STAGE((t + 1) & 1, (t + 1) * 128);
        const ushort* Kb = Klds[t & 1];
        const ushort* Vb = Vtlds[t & 1];

        #pragma unroll
        for (int hh = 0; hh < 2; ++hh) {
            bf16x8 kf[2][2];
            #pragma unroll
            for (int kt = 0; kt < 2; ++kt)
                #pragma unroll
                for (int ph = 0; ph < 2; ++ph) {
                    int slot = (2 * ph + hi) ^ ((c32 >> 1) & 3);
                    kf[kt][ph] = *(const bf16x8*)&Kb[(hh * 64 + kt * 32 + c32) * 32 + slot * 8];
                }
            bf16x8 vf[4];
            #pragma unroll
            for (int j = 0; j < 4; ++j) {
                int slot = (hh * 8 + 2 * j + hi) ^ (c32 & 15);
                vf[j] = *(const bf16x8*)&Vb[c32 * 128 + slot * 8];
            }

            f32x16 st[2];
            __builtin_amdgcn_s_setprio(1);
            #pragma unroll
            for (int kt = 0; kt < 2; ++kt) {
                st[kt] = __builtin_amdgcn_mfma_f32_32x32x16_bf16(kf[kt][0], qfrag[0], zero16, 0, 0, 0);
                st[kt] = __builtin_amdgcn_mfma_f32_32x32x16_bf16(kf[kt][1], qfrag[1], st[kt], 0, 0, 0);
            }
            __builtin_amdgcn_s_setprio(0);

            float r0 = 0.f, r1 = 0.f, r2 = 0.f, r3 = 0.f;
            #pragma unroll
            for (int kt = 0; kt < 2; ++kt) {
                #pragma unroll
                for (int i = 0; i < 4; ++i) {
                    float p0 = exp2_fast(st[kt][i * 4 + 0]);
                    float p1 = exp2_fast(st[kt][i * 4 + 1]);
                    float p2 = exp2_fast(st[kt][i * 4 + 2]);
                    float p3 = exp2_fast(st[kt][i * 4 + 3]);
                    st[kt][i * 4 + 0] = p0; r0 += p0;
                    st[kt][i * 4 + 1] = p1; r1 += p1;
                    st[kt][i * 4 + 2] = p2; r2 += p2;
                    st[kt][i * 4 + 3] = p3; r3 += p3;
                }
            }
            float rsum = (r0 + r1) + (r2 + r3);
            rsum += __shfl_xor(rsum, 32);
            l += rsum;

            unsigned wpk[2][4][2];
            #pragma unroll
            for (int kt = 0; kt < 2; ++kt)
                #pragma unroll
                for (int rg = 0; rg < 4; ++rg) {
                    wpk[kt][rg][0] = cvtpk_bf16(st[kt][rg * 4 + 0], st[kt][rg * 4 + 1]);
                    wpk[kt][rg][1] = cvtpk_bf16(st[kt][rg * 4 + 2], st[kt][rg * 4 + 3]);
                }

            __builtin_amdgcn_s_setprio(1);
            #pragma unroll
            for (int j = 0; j < 4; ++j) {
                int kt = j >> 1, rg0 = 2 * (j & 1);
                unsigned x0 = wpk[kt][rg0][0], y0 = wpk[kt][rg0 + 1][0];
                unsigned x1 = wpk[kt][rg0][1], y1 = wpk[kt][rg0 + 1][1];
                asm("v_permlane32_swap_b32 %0, %1" : "+v"(x0), "+v"(y0));
                asm("v_permlane32_swap_b32 %0, %1" : "+v"(x1), "+v"(y1));
                union { unsigned u[4]; bf16x8 v; } pf;
                pf.u[0] = x0; pf.u[1] = x1; pf.u[2] = y0; pf.u[3] = y1;
                oacc = __builtin_amdgcn_mfma_f32_32x32x16_bf16(vf[j], pf.v, oacc, 0, 0, 0);
            }
            __builtin_amdgcn_s_setprio(0);
        }
    }
#undef STAGE

    const float inv = 1.0f / l;
    const int row2 = h * 128 + (n >> 4);
    const int colb = (n & 15) * PD;
    const size_t rowoff = (rowbase + row2) * DIM;

    float xv[16];
    float s = 0.f, ss = 0.f;
    #pragma unroll
    for (int ch = 0; ch < 4; ++ch) {
        float4 r4 = *(const float4*)&res[rowoff + colb + ch * 8 + hi * 4];
        #pragma unroll
        for (int q = 0; q < 4; ++q) {
            float rv = (q == 0) ? r4.x : (q == 1) ? r4.y : (q == 2) ? r4.z : r4.w;
            float x = rv + oacc[ch * 4 + q] * inv;
            xv[ch * 4 + q] = x; s += x; ss += x * x;
        }
    }
    s += __shfl_xor(s, 1);  ss += __shfl_xor(ss, 1);
    s += __shfl_xor(s, 2);  ss += __shfl_xor(ss, 2);
    s += __shfl_xor(s, 4);  ss += __shfl_xor(ss, 4);
    s += __shfl_xor(s, 8);  ss += __shfl_xor(ss, 8);
    s += __shfl_xor(s, 32); ss += __shfl_xor(ss, 32);
    float mu = s * (1.0f / DIM);
    float var = ss * (1.0f / DIM) - mu * mu;
    float rr = rsqrtf(var + 1e-5f);

    #pragma unroll
    for (int ch = 0; ch < 4; ++ch) {
        const int off = colb + ch * 8 + hi * 4;
        float4 g4 = *(const float4*)&gptr[off];
        float4 b4 = *(const float4*)&bptr[off];
        float y0 = (xv[ch * 4 + 0] - mu) * rr * g4.x + b4.x;
        float y1 = (xv[ch * 4 + 1] - mu) * rr * g4.y + b4.y;
        float y2 = (xv[ch * 4 + 2] - mu) * rr * g4.z + b4.z;
        float y3 = (xv[ch * 4 + 3] - mu) * rr * g4.w + b4.w;
        float4 yv = {y0, y1, y2, y3};
        *(float4*)&nf32[rowoff + off] = yv;
        uint2 pk = {cvtpk_bf16(y0, y1), cvtpk_bf16(y2, y3)};
        *(uint2*)&nb16[rowoff + off] = pk;
    }
}

extern "C" void kernel_launch(void* const* d_in, const int* in_sizes, int n_in,
                              void* d_out, int out_size, void* d_ws, size_t ws_size,
                              hipStream_t stream)
{
    const float* x1     = (const float*)d_in[0];
    const float* x2     = (const float*)d_in[1];
    const float* qkv_w  = (const float*)d_in[2];
    const float* qkv_b  = (const float*)d_in[3];
    const float* q_w    = (const float*)d_in[4];
    const float* q_b    = (const float*)d_in[5];
    const float* kv_w   = (const float*)d_in[6];
    const float* kv_b   = (const float*)d_in[7];
    const float* norm_g = (const float*)d_in[8];
    const float* norm_b = (const float*)d_in[9];
    const float* fc1_w  = (const float*)d_in[10];
    const float* fc1_b  = (const float*)d_in[11];
    const float* fc2_w  = (const float*)d_in[12];
    const float* fc2_b  = (const float*)d_in[13];
    float* out = (float*)d_out;
    float* ws  = (float*)d_ws;

    const int M = BATCH * NSEQ;  // 8192
    const int BIG = 1 << 30;

    // ws layout (float offsets), 84 MB total:
    // [0,2M) weights | [2M,10M) proj_u | [10.5M,12.5M) VtG
    // [13M,17M) n1f32 | [17M,19M) n1b16 (alias x1b, temporally disjoint)
    // [19M,21M) n2b16 (alias x2b, temporally disjoint)
    ushort* wtb    = (ushort*)ws;
    ushort* q_wt   = wtb;
    ushort* kv_wt  = wtb + 262144;
    ushort* qkv_wt = wtb + 786432;
    ushort* fc1_wt = wtb + 1572864;
    ushort* fc2_wt = wtb + 2621440;
    ushort* proj_u = (ushort*)(ws + (size_t)2 * 1024 * 1024);
    ushort* kvb16  = proj_u;                            // 8192x1024
    ushort* qb16   = proj_u + (size_t)8192 * 1024;      // 8192x512
    ushort* qkvb16 = proj_u;                            // 8192x1536
    ushort* hbuf   = proj_u;                            // 8192x2048
    ushort* VtG    = (ushort*)(ws + (size_t)21 * 512 * 1024);  // 10.5M floats
    float*  n1f32  = ws + (size_t)13 * 1024 * 1024;
    ushort* n1b16  = (ushort*)(ws + (size_t)17 * 1024 * 1024);
    ushort* n2b16  = (ushort*)(ws + (size_t)19 * 1024 * 1024);
    ushort* x1b    = n1b16;   // alias, temporally disjoint
    ushort* x2b    = n2b16;   // alias, temporally disjoint

    dim3 blk(256);

    tr_all_kernel<<<dim3(7680), blk, 0, stream>>>(
        q_w, kv_w, qkv_w, fc1_w, fc2_w, wtb, x1, x2, x1b, x2b);

    // ---- cross attention ----
    mgemm_bf<3, 4><<<dim3(1024 / 128, M / 128), blk, 0, stream>>>(
        x1b, kv_wt, kv_b, nullptr, kvb16, VtG, M, DIM, 1024, 0, 512);
    mgemm_bf<3, 2><<<dim3(512 / 64, M / 128), blk, 0, stream>>>(
        x2b, q_wt, q_b, nullptr, qb16, nullptr, M, DIM, 512, 512, BIG);
    attn_mfma_kernel<<<dim3(1024), blk, 0, stream>>>(
        qb16, 512, 0, kvb16, 1024, 0, VtG, x2, norm_g, norm_b, n1f32, n1b16);

    // ---- self attention ----
    mgemm_bf<3, 4><<<dim3(1536 / 128, M / 128), blk, 0, stream>>>(
        n1b16, qkv_wt, qkv_b, nullptr, qkvb16, VtG, M, DIM, 1536, 512, 1024);
    attn_mfma_kernel<<<dim3(1024), blk, 0, stream>>>(
        qkvb16, 1536, 0, qkvb16, 1536, 512, VtG, n1f32, norm_g, norm_b, n1f32, n2b16);

    // ---- MLP ----
    mgemm_bf<1, 4><<<dim3(HIDDEN / 128, M / 128), blk, 0, stream>>>(
        n2b16, fc1_wt, fc1_b, nullptr, hbuf, nullptr, M, DIM, HIDDEN, 0, BIG);
    mgemm_bf<2, 2><<<dim3(512 / 64, M / 128), blk, 0, stream>>>(
        hbuf, fc2_wt, fc2_b, n1f32, out, nullptr, M, HIDDEN, DIM, 0, BIG);
}